// Round 1
// 1361.260 us; speedup vs baseline: 3.2550x; 3.2550x over previous
//
#include <hip/hip_runtime.h>

// GRU scan T=1024,B=256,D=H=256 — 3-kernel design:
//  1) transpose_w: Wi,Wh (f32 [256][768]) -> Wt,Wht (bf16 [768][256], k-fast)
//  2) gi_gemm: per 128-step window, gi = x @ Wi  (full chip, no seq dependency)
//  3) rec_kernel: CHUNK-PARALLEL recurrence. resets (p=0.5) break the h-chain:
//     each block owns ONE batch row b; its 16 MFMA A-rows are 16 independent
//     time-chunks of that row, each starting at an actual reset (h provably 0)
//     found by an in-kernel scan of the window's reset flags. 256 blocks ->
//     full chip; steps/window drop 128 -> max chunk len (~12-16).
//     Degenerate resets (no resets) => 1 chunk/row => old behavior (correct).

typedef __attribute__((ext_vector_type(8))) short sv8;
typedef __attribute__((ext_vector_type(4))) short sv4;
typedef __attribute__((ext_vector_type(4))) float fv4;

#define HPAD 264
#define GAP 40

static __device__ __forceinline__ unsigned short f2bf(float f) {
  unsigned int u = __float_as_uint(f);
  u += 0x7fffu + ((u >> 16) & 1u);  // RNE
  return (unsigned short)(u >> 16);
}
static __device__ __forceinline__ float bf2f(unsigned short s) {
  return __uint_as_float(((unsigned int)s) << 16);
}

// ---------------- kernel 1: weight transpose + bf16 cast ----------------
__global__ __launch_bounds__(256) void transpose_w(
    const float* __restrict__ Wi, const float* __restrict__ Wh,
    unsigned short* __restrict__ Wt, unsigned short* __restrict__ Wht) {
  __shared__ float tile[32][33];
  const int bid = blockIdx.x;                 // 0..383
  const float* src = (bid < 192) ? Wi : Wh;
  unsigned short* dst = (bid < 192) ? Wt : Wht;
  const int local = bid % 192;
  const int c0 = (local % 24) * 32;           // col in [0,768)
  const int k0 = (local / 24) * 32;           // k in [0,256)
  const int t = threadIdx.x, tr = t >> 5, tc = t & 31;
#pragma unroll
  for (int p = 0; p < 4; ++p) {
    int k = tr + p * 8;
    tile[k][tc] = src[(size_t)(k0 + k) * 768 + c0 + tc];
  }
  __syncthreads();
#pragma unroll
  for (int p = 0; p < 4; ++p) {
    int c = tr + p * 8;
    dst[(size_t)(c0 + c) * 256 + k0 + tc] = f2bf(tile[tc][c]);
  }
}

// ---------------- kernel 2: gi = x @ Wi for a window ----------------
// grid (wsteps*2, 6), 256 thr. BM=BN=128, BK=32.
__global__ __launch_bounds__(256) void gi_gemm(
    const float* __restrict__ ins, const unsigned short* __restrict__ Wt,
    unsigned short* __restrict__ gi, int w0) {
  __shared__ __align__(16) unsigned short As[128][GAP];
  __shared__ __align__(16) unsigned short Bs[128][GAP];
  const int t = threadIdx.x;
  const int m0 = blockIdx.x * 128;
  const int n0 = blockIdx.y * 128;
  const int wave = t >> 6, lane = t & 63;
  const int n16 = lane & 15, quad = lane >> 4;
  const int m0w = (wave & 1) * 64, n0w = (wave >> 1) * 64;

  fv4 acc[4][4] = {};
  for (int kb = 0; kb < 8; ++kb) {
    // stage A: x rows (f32 -> bf16)
#pragma unroll
    for (int r = 0; r < 4; ++r) {
      const int m = (t >> 3) + r * 32;
      const int kk = (t & 7) * 4;
      const int grow = m0 + m;  // (lt,b) row
      const float* xp = ins + ((size_t)(w0 + (grow >> 8)) * 256 + (grow & 255)) * 256 + kb * 32 + kk;
      fv4 v = *(const fv4*)xp;
      sv4 pk = {(short)f2bf(v[0]), (short)f2bf(v[1]), (short)f2bf(v[2]), (short)f2bf(v[3])};
      *(sv4*)&As[m][kk] = pk;
    }
    // stage B: straight bf16 copy from pre-transposed Wt
    {
      const int n = t >> 1, kh = (t & 1) * 16;
      const sv8* wp = (const sv8*)(Wt + (size_t)(n0 + n) * 256 + kb * 32 + kh);
      *(sv8*)&Bs[n][kh] = wp[0];
      *(sv8*)&Bs[n][kh + 8] = wp[1];
    }
    __syncthreads();
    sv8 af[4], bfr[4];
#pragma unroll
    for (int mt = 0; mt < 4; ++mt) af[mt] = *(const sv8*)&As[m0w + mt * 16 + n16][quad * 8];
#pragma unroll
    for (int nt = 0; nt < 4; ++nt) bfr[nt] = *(const sv8*)&Bs[n0w + nt * 16 + n16][quad * 8];
#pragma unroll
    for (int mt = 0; mt < 4; ++mt)
#pragma unroll
      for (int nt = 0; nt < 4; ++nt)
        acc[mt][nt] = __builtin_amdgcn_mfma_f32_16x16x32_bf16(af[mt], bfr[nt], acc[mt][nt], 0, 0, 0);
    __syncthreads();
  }
#pragma unroll
  for (int mt = 0; mt < 4; ++mt)
#pragma unroll
    for (int i = 0; i < 4; ++i) {
      const int row = m0 + m0w + mt * 16 + quad * 4 + i;
      unsigned short* gp = gi + (size_t)row * 768 + n0 + n0w + n16;
#pragma unroll
      for (int nt = 0; nt < 4; ++nt) gp[nt * 16] = f2bf(acc[mt][nt][i]);
    }
}

// ---------------- kernel 3: chunk-parallel recurrent scan ----------------
// grid = 256 blocks (one per batch row), 1024 thr (16 waves).
// Block b: 16 A-rows = 16 time-chunks of batch row b within [t0, t0+wsteps).
// Chunk r starts at cstart[r]; cstart[0]=0 (continues h_in), cstart[r>=1] is
// the first reset in [r*L, r*L+L) (L=wsteps/16). Missing boundaries merge.
// All chunks step in lockstep s=0..smax-1; row r processes lt = cstart[r]+s
// while s < len_r. Chunk starts (r>=1) have reset=1 so h=0 there: chunks are
// exactly independent under the reference semantics.
__global__ __launch_bounds__(1024) void rec_kernel(
    const unsigned short* __restrict__ gi,   // [wsteps*256][768] bf16
    const int* __restrict__ resets,          // [T][B] int32
    const float* __restrict__ h_in,          // [B][H] f32 (init_h or h_carry)
    float* __restrict__ h_carry,             // [B][H] f32
    const unsigned short* __restrict__ Wht,  // [768][256] bf16 transposed
    const float* __restrict__ bias,          // [768] f32
    float* __restrict__ out,                 // [T][B][H] f32
    int t0, int wsteps) {
  __shared__ __align__(16) unsigned short whn[256][HPAD];     // Wh_n, [col][k]
  __shared__ __align__(16) unsigned short hbuf[2][16][HPAD];  // h bf16 (16 chunks)
  __shared__ int cand[16];
  __shared__ int cstart[17];
  __shared__ int s_smax;

  const int tid = threadIdx.x;
  const int wave = tid >> 6, lane = tid & 63;
  const int n16 = lane & 15, quad = lane >> 4;
  const int b = blockIdx.x;  // batch row owned by this block
  const int wcb = wave * 16;

  // stage Wh_n (cols 512..767 of Wht) into LDS
  for (int e = tid; e < 8192; e += 1024) {
    const int col = e >> 5, kc = (e & 31) * 8;
    *(sv8*)&whn[col][kc] = *(const sv8*)(Wht + (size_t)(512 + col) * 256 + kc);
  }
  // Wh_r / Wh_z B-frags in VGPRs
  sv8 whf[2][8];
#pragma unroll
  for (int g = 0; g < 2; ++g)
#pragma unroll
    for (int kt = 0; kt < 8; ++kt)
      whf[g][kt] = *(const sv8*)(Wht + (size_t)(g * 256 + wcb + n16) * 256 + kt * 32 + quad * 8);

  const float b_r = bias[wcb + n16];
  const float b_z = bias[256 + wcb + n16];
  const float b_n = bias[512 + wcb + n16];

  // ---- chunk boundaries from the actual resets of this window ----
  if (tid < 16) cand[tid] = wsteps;
  __syncthreads();
  {
    int LCH = wsteps >> 4;
    if (LCH < 1) LCH = 1;
    if (tid < wsteps) {
      const int f = resets[(size_t)(t0 + tid) * 256 + b];
      const int j = tid / LCH;
      if (f && j >= 1 && j < 16) atomicMin(&cand[j], tid);
    }
  }
  // stage hbuf[0]: chunk 0 = bf16(h_in[b]) pre-masked by resets[t0]; others 0
  {
    const int row = tid >> 6, c4 = (tid & 63) * 4;
    sv4 pk = {0, 0, 0, 0};
    if (row == 0) {
      const int f0 = resets[(size_t)t0 * 256 + b];
      if (!f0) {
        fv4 v = *(const fv4*)(h_in + (size_t)b * 256 + c4);
#pragma unroll
        for (int j = 0; j < 4; ++j) pk[j] = (short)f2bf(v[j]);
      }
    }
    *(sv4*)&hbuf[0][row][c4] = pk;
  }
  __syncthreads();
  if (tid == 0) {
    int cnt = 1;
    cstart[0] = 0;
    for (int j = 1; j < 16; ++j)
      if (cand[j] < wsteps) cstart[cnt++] = cand[j];
    for (int r = cnt; r <= 16; ++r) cstart[r] = wsteps;
    int mx = 0;
    for (int r = 0; r < 16; ++r) {
      const int L = cstart[r + 1] - cstart[r];
      if (L > mx) mx = L;
    }
    s_smax = mx;
  }
  __syncthreads();

  int rs_[4], rl_[4];
#pragma unroll
  for (int i = 0; i < 4; ++i) {
    const int ri = quad * 4 + i;
    rs_[i] = cstart[ri];
    rl_[i] = cstart[ri + 1] - rs_[i];
  }
  float hprev[4];
#pragma unroll
  for (int i = 0; i < 4; ++i)
    hprev[i] = (rs_[i] == 0) ? h_in[(size_t)b * 256 + wcb + n16] : 0.f;

  const int smax = s_smax;
  const unsigned short* gb = gi + (size_t)b * 768 + wcb + n16;
  const int* rbase = resets + (size_t)t0 * 256 + b;
  float* ob = out + (size_t)t0 * 65536 + (size_t)b * 256 + wcb + n16;

  for (int s = 0; s < smax; ++s) {
    const int rb = s & 1, wb = rb ^ 1;

    unsigned short gr[4], gz[4], gn[4];
    int rc[4], nf[4], lt[4];
#pragma unroll
    for (int i = 0; i < 4; ++i) {
      lt[i] = rs_[i] + s;
      if (s < rl_[i]) {
        const unsigned short* g0 = gb + (size_t)lt[i] * 196608;
        gr[i] = g0[0];
        gz[i] = g0[256];
        gn[i] = g0[512];
        rc[i] = rbase[lt[i] * 256];
        nf[i] = (s + 1 < rl_[i]) ? rbase[(lt[i] + 1) * 256] : 0;
      } else {
        gr[i] = gz[i] = gn[i] = 0;
        rc[i] = 1;
        nf[i] = 0;
      }
    }

    fv4 acc_r = {}, acc_z = {}, acc_n = {};
#pragma unroll
    for (int kt = 0; kt < 8; ++kt) {
      sv8 hf = *(const sv8*)&hbuf[rb][n16][kt * 32 + quad * 8];
      sv8 wnf = *(const sv8*)&whn[wcb + n16][kt * 32 + quad * 8];
      acc_r = __builtin_amdgcn_mfma_f32_16x16x32_bf16(hf, whf[0][kt], acc_r, 0, 0, 0);
      acc_z = __builtin_amdgcn_mfma_f32_16x16x32_bf16(hf, whf[1][kt], acc_z, 0, 0, 0);
      acc_n = __builtin_amdgcn_mfma_f32_16x16x32_bf16(hf, wnf, acc_n, 0, 0, 0);
    }

#pragma unroll
    for (int i = 0; i < 4; ++i) {
      const float pre_r = bf2f(gr[i]) + acc_r[i] + b_r;
      const float pre_z = bf2f(gz[i]) + acc_z[i] + b_z;
      const float r = __builtin_amdgcn_rcpf(1.f + __expf(-pre_r));
      const float z = __builtin_amdgcn_rcpf(1.f + __expf(-pre_z));
      const float npre = bf2f(gn[i]) + r * (acc_n[i] + b_n);
      const float n = 1.f - 2.f * __builtin_amdgcn_rcpf(1.f + __expf(2.f * npre));
      const float hp = rc[i] ? 0.f : hprev[i];
      const float hnew = (1.f - z) * n + z * hp;
      hprev[i] = hnew;
      if (s < rl_[i]) {
        ob[(size_t)lt[i] * 65536] = hnew;
        if (lt[i] == wsteps - 1) h_carry[(size_t)b * 256 + wcb + n16] = hnew;
      }
      unsigned short hb = 0;
      if (s + 1 < rl_[i] && !nf[i]) hb = f2bf(hnew);
      hbuf[wb][quad * 4 + i][wcb + n16] = hb;
    }
    __syncthreads();
  }
}

extern "C" void kernel_launch(void* const* d_in, const int* in_sizes, int n_in,
                              void* d_out, int out_size, void* d_ws, size_t ws_size,
                              hipStream_t stream) {
  const float* ins    = (const float*)d_in[0];
  const int* resets   = (const int*)d_in[1];
  const float* init_h = (const float*)d_in[2];
  const float* Wi     = (const float*)d_in[3];
  const float* Wh     = (const float*)d_in[4];
  const float* bias   = (const float*)d_in[5];
  float* out          = (float*)d_out;

  char* ws = (char*)d_ws;
  unsigned short* Wt  = (unsigned short*)ws;              // 393216 B
  unsigned short* Wht = (unsigned short*)(ws + 393216);   // 393216 B
  float* h_carry      = (float*)(ws + 786432);            // 262144 B
  unsigned short* gi  = (unsigned short*)(ws + 1048576);

  int wsteps = 128;
  while (wsteps > 2 && (size_t)1048576 + (size_t)wsteps * 256 * 768 * 2 > ws_size) wsteps >>= 1;
  const int nwin = 1024 / wsteps;

  hipLaunchKernelGGL(transpose_w, dim3(384), dim3(256), 0, stream, Wi, Wh, Wt, Wht);
  for (int w = 0; w < nwin; ++w) {
    const int t0 = w * wsteps;
    hipLaunchKernelGGL(gi_gemm, dim3(wsteps * 2, 6), dim3(256), 0, stream, ins, Wt, gi, t0);
    hipLaunchKernelGGL(rec_kernel, dim3(256), dim3(1024), 0, stream,
                       gi, resets, (w == 0 ? init_h : h_carry), h_carry, Wht, bias, out, t0, wsteps);
  }
}

// Round 2
// 1062.002 us; speedup vs baseline: 4.1722x; 1.2818x over previous
//
#include <hip/hip_runtime.h>

// GRU scan T=1024,B=256,D=H=256 — 3-kernel design:
//  1) transpose_w: Wi,Wh (f32 [256][768]) -> Wt,Wht (bf16 [768][256], k-fast)
//  2) gi_gemm: gi = x @ Wi for the whole window (full chip)
//  3) rec_kernel: CHUNK-PARALLEL recurrence, 512 thr / 8 waves / 2 col-tiles.
//     Each block owns ONE batch row; 16 MFMA A-rows = 16 time-chunks starting
//     at actual resets (suffix-min boundary pick). Per-step critical path cut:
//     raw s_barrier with lgkmcnt-only wait (no vmcnt drain of output stores),
//     r/z weights truly in VGPRs (launch_bounds(512,2) -> 256-reg budget),
//     resets in LDS, gi prefetched one step ahead in ping-pong registers.
//     ws_size >= 1GiB (fill counters) -> wsteps=1024: ONE window, no h_carry.

typedef __attribute__((ext_vector_type(8))) short sv8;
typedef __attribute__((ext_vector_type(4))) short sv4;
typedef __attribute__((ext_vector_type(4))) float fv4;

#define HPAD 264
#define GAP 40

static __device__ __forceinline__ unsigned short f2bf(float f) {
  unsigned int u = __float_as_uint(f);
  u += 0x7fffu + ((u >> 16) & 1u);  // RNE
  return (unsigned short)(u >> 16);
}
static __device__ __forceinline__ float bf2f(unsigned short s) {
  return __uint_as_float(((unsigned int)s) << 16);
}

// ---------------- kernel 1: weight transpose + bf16 cast ----------------
__global__ __launch_bounds__(256) void transpose_w(
    const float* __restrict__ Wi, const float* __restrict__ Wh,
    unsigned short* __restrict__ Wt, unsigned short* __restrict__ Wht) {
  __shared__ float tile[32][33];
  const int bid = blockIdx.x;                 // 0..383
  const float* src = (bid < 192) ? Wi : Wh;
  unsigned short* dst = (bid < 192) ? Wt : Wht;
  const int local = bid % 192;
  const int c0 = (local % 24) * 32;           // col in [0,768)
  const int k0 = (local / 24) * 32;           // k in [0,256)
  const int t = threadIdx.x, tr = t >> 5, tc = t & 31;
#pragma unroll
  for (int p = 0; p < 4; ++p) {
    int k = tr + p * 8;
    tile[k][tc] = src[(size_t)(k0 + k) * 768 + c0 + tc];
  }
  __syncthreads();
#pragma unroll
  for (int p = 0; p < 4; ++p) {
    int c = tr + p * 8;
    dst[(size_t)(c0 + c) * 256 + k0 + tc] = f2bf(tile[tc][c]);
  }
}

// ---------------- kernel 2: gi = x @ Wi for a window ----------------
// grid (wsteps*2, 6), 256 thr. BM=BN=128, BK=32.
__global__ __launch_bounds__(256) void gi_gemm(
    const float* __restrict__ ins, const unsigned short* __restrict__ Wt,
    unsigned short* __restrict__ gi, int w0) {
  __shared__ __align__(16) unsigned short As[128][GAP];
  __shared__ __align__(16) unsigned short Bs[128][GAP];
  const int t = threadIdx.x;
  const int m0 = blockIdx.x * 128;
  const int n0 = blockIdx.y * 128;
  const int wave = t >> 6, lane = t & 63;
  const int n16 = lane & 15, quad = lane >> 4;
  const int m0w = (wave & 1) * 64, n0w = (wave >> 1) * 64;

  fv4 acc[4][4] = {};
  for (int kb = 0; kb < 8; ++kb) {
    // stage A: x rows (f32 -> bf16)
#pragma unroll
    for (int r = 0; r < 4; ++r) {
      const int m = (t >> 3) + r * 32;
      const int kk = (t & 7) * 4;
      const int grow = m0 + m;  // (lt,b) row
      const float* xp = ins + ((size_t)(w0 + (grow >> 8)) * 256 + (grow & 255)) * 256 + kb * 32 + kk;
      fv4 v = *(const fv4*)xp;
      sv4 pk = {(short)f2bf(v[0]), (short)f2bf(v[1]), (short)f2bf(v[2]), (short)f2bf(v[3])};
      *(sv4*)&As[m][kk] = pk;
    }
    // stage B: straight bf16 copy from pre-transposed Wt
    {
      const int n = t >> 1, kh = (t & 1) * 16;
      const sv8* wp = (const sv8*)(Wt + (size_t)(n0 + n) * 256 + kb * 32 + kh);
      *(sv8*)&Bs[n][kh] = wp[0];
      *(sv8*)&Bs[n][kh + 8] = wp[1];
    }
    __syncthreads();
    sv8 af[4], bfr[4];
#pragma unroll
    for (int mt = 0; mt < 4; ++mt) af[mt] = *(const sv8*)&As[m0w + mt * 16 + n16][quad * 8];
#pragma unroll
    for (int nt = 0; nt < 4; ++nt) bfr[nt] = *(const sv8*)&Bs[n0w + nt * 16 + n16][quad * 8];
#pragma unroll
    for (int mt = 0; mt < 4; ++mt)
#pragma unroll
      for (int nt = 0; nt < 4; ++nt)
        acc[mt][nt] = __builtin_amdgcn_mfma_f32_16x16x32_bf16(af[mt], bfr[nt], acc[mt][nt], 0, 0, 0);
    __syncthreads();
  }
#pragma unroll
  for (int mt = 0; mt < 4; ++mt)
#pragma unroll
    for (int i = 0; i < 4; ++i) {
      const int row = m0 + m0w + mt * 16 + quad * 4 + i;
      unsigned short* gp = gi + (size_t)row * 768 + n0 + n0w + n16;
#pragma unroll
      for (int nt = 0; nt < 4; ++nt) gp[nt * 16] = f2bf(acc[mt][nt][i]);
    }
}

// ---------------- kernel 3: chunk-parallel recurrent scan ----------------
// grid = 256 blocks (one per batch row), 512 thr (8 waves x 2 col-tiles).
__global__ __launch_bounds__(512, 2) void rec_kernel(
    const unsigned short* __restrict__ gi,   // [wsteps*256][768] bf16
    const int* __restrict__ resets,          // [T][B] int32
    const float* __restrict__ h_in,          // [B][H] f32
    float* __restrict__ h_carry,             // [B][H] f32
    const unsigned short* __restrict__ Wht,  // [768][256] bf16 transposed
    const float* __restrict__ bias,          // [768] f32
    float* __restrict__ out,                 // [T][B][H] f32
    int t0, int wsteps) {
  __shared__ __align__(16) unsigned short whn[256][HPAD];     // Wh_n, [col][k]
  __shared__ __align__(16) unsigned short hbuf[2][16][HPAD];  // h bf16 (16 chunks)
  __shared__ int rstl[1024];
  __shared__ int cand[16];
  __shared__ int cstart[17];
  __shared__ int s_smax;

  const int tid = threadIdx.x;
  const int wave = tid >> 6, lane = tid & 63;
  const int n16 = lane & 15, quad = lane >> 4;
  const int b = blockIdx.x;  // batch row owned by this block
  const int wcb = wave * 16;

  // stage Wh_n (cols 512..767 of Wht) into LDS
  for (int e = tid; e < 8192; e += 512) {
    const int col = e >> 5, kc = (e & 31) * 8;
    *(sv8*)&whn[col][kc] = *(const sv8*)(Wht + (size_t)(512 + col) * 256 + kc);
  }
  // stage this row's reset flags for the window
  for (int e = tid; e < wsteps; e += 512)
    rstl[e] = resets[(size_t)(t0 + e) * 256 + b];
  if (tid < 16) cand[tid] = wsteps;
  __syncthreads();

  // first reset per span
  {
    int span = wsteps >> 4;
    if (span < 1) span = 1;
    for (int e = tid; e < wsteps; e += 512)
      if (rstl[e]) {
        const int j = e / span;
        if (j < 16) atomicMin(&cand[j], e);
      }
  }
  // hbuf[0]: chunk 0 = bf16(h_in[b]) pre-masked by resets[t0]; rows 1..15 = 0
  {
    const int row = tid >> 5, c8 = (tid & 31) * 8;
    sv8 pk = {0, 0, 0, 0, 0, 0, 0, 0};
    if (row == 0 && !rstl[0]) {
      fv4 v0 = *(const fv4*)(h_in + (size_t)b * 256 + c8);
      fv4 v1 = *(const fv4*)(h_in + (size_t)b * 256 + c8 + 4);
#pragma unroll
      for (int j = 0; j < 4; ++j) pk[j] = (short)f2bf(v0[j]);
#pragma unroll
      for (int j = 0; j < 4; ++j) pk[4 + j] = (short)f2bf(v1[j]);
    }
    *(sv8*)&hbuf[0][row][c8] = pk;
  }
  __syncthreads();
  if (tid == 0) {
    // S[r] = first reset >= r*span (suffix-min over span candidates), dedup
    int span = wsteps >> 4;
    if (span < 1) span = 1;
    int S[17];
    S[16] = wsteps;
    for (int j = 15; j >= 0; --j) S[j] = (cand[j] < wsteps) ? cand[j] : S[j + 1];
    int cnt = 1;
    cstart[0] = 0;
    for (int r = 1; r < 16; ++r) {
      const int v = S[r];
      if (v < wsteps && v > cstart[cnt - 1]) cstart[cnt++] = v;
    }
    for (int r = cnt; r <= 16; ++r) cstart[r] = wsteps;
    int mx = 0;
    for (int r = 0; r < 16; ++r) {
      const int L = cstart[r + 1] - cstart[r];
      if (L > mx) mx = L;
    }
    s_smax = mx;
  }
  __syncthreads();

  int rs_[4], rl_[4];
#pragma unroll
  for (int i = 0; i < 4; ++i) {
    const int ri = quad * 4 + i;
    rs_[i] = cstart[ri];
    rl_[i] = cstart[ri + 1] - rs_[i];
  }
  float hprev[4][2];
#pragma unroll
  for (int i = 0; i < 4; ++i)
#pragma unroll
    for (int c = 0; c < 2; ++c)
      hprev[i][c] = (rs_[i] == 0) ? h_in[(size_t)b * 256 + c * 128 + wcb + n16] : 0.f;

  // Wh_r / Wh_z B-frags genuinely in VGPRs (256-reg budget at 8 waves)
  sv8 whf[2][2][8];
#pragma unroll
  for (int g = 0; g < 2; ++g)
#pragma unroll
    for (int c = 0; c < 2; ++c)
#pragma unroll
      for (int kt = 0; kt < 8; ++kt)
        whf[g][c][kt] = *(const sv8*)(Wht + (size_t)(g * 256 + c * 128 + wcb + n16) * 256 + kt * 32 + quad * 8);

  float b_r[2], b_z[2], b_n[2];
#pragma unroll
  for (int c = 0; c < 2; ++c) {
    const int col = c * 128 + wcb + n16;
    b_r[c] = bias[col];
    b_z[c] = bias[256 + col];
    b_n[c] = bias[512 + col];
  }

  const unsigned short* gbase = gi + (size_t)b * 768 + wcb + n16;
  float* ob0 = out + (size_t)t0 * 65536 + (size_t)b * 256 + wcb + n16;
  const int smax = s_smax;

  auto prefetch = [&](int s, unsigned short (&dst)[2][3][4]) {
#pragma unroll
    for (int i = 0; i < 4; ++i) {
      int lt = rs_[i] + s;
      if (lt > wsteps - 1) lt = wsteps - 1;
      const unsigned short* g0 = gbase + (size_t)lt * 196608;
#pragma unroll
      for (int c = 0; c < 2; ++c) {
        dst[c][0][i] = g0[c * 128];
        dst[c][1][i] = g0[c * 128 + 256];
        dst[c][2][i] = g0[c * 128 + 512];
      }
    }
  };

  auto step = [&](int s, unsigned short (&cur)[2][3][4], unsigned short (&nxt)[2][3][4]) {
    const int rb = s & 1, wb = rb ^ 1;
    fv4 acc[3][2] = {};
#pragma unroll
    for (int kt = 0; kt < 8; ++kt) {
      sv8 hf = *(const sv8*)&hbuf[rb][n16][kt * 32 + quad * 8];
#pragma unroll
      for (int c = 0; c < 2; ++c) {
        sv8 wnf = *(const sv8*)&whn[c * 128 + wcb + n16][kt * 32 + quad * 8];
        acc[0][c] = __builtin_amdgcn_mfma_f32_16x16x32_bf16(hf, whf[0][c][kt], acc[0][c], 0, 0, 0);
        acc[1][c] = __builtin_amdgcn_mfma_f32_16x16x32_bf16(hf, whf[1][c][kt], acc[1][c], 0, 0, 0);
        acc[2][c] = __builtin_amdgcn_mfma_f32_16x16x32_bf16(hf, wnf, acc[2][c], 0, 0, 0);
      }
    }
    prefetch(s + 1, nxt);  // in flight across the barrier, consumed next step
#pragma unroll
    for (int i = 0; i < 4; ++i) {
      const int lt = rs_[i] + s;
      const bool act = (s < rl_[i]);
      const int rcur = act ? rstl[lt] : 1;
      const int nf = (s + 1 < rl_[i]) ? rstl[lt + 1] : 1;
#pragma unroll
      for (int c = 0; c < 2; ++c) {
        const float pre_r = bf2f(cur[c][0][i]) + acc[0][c][i] + b_r[c];
        const float pre_z = bf2f(cur[c][1][i]) + acc[1][c][i] + b_z[c];
        const float r = __builtin_amdgcn_rcpf(1.f + __expf(-pre_r));
        const float z = __builtin_amdgcn_rcpf(1.f + __expf(-pre_z));
        const float npre = bf2f(cur[c][2][i]) + r * (acc[2][c][i] + b_n[c]);
        const float n = 1.f - 2.f * __builtin_amdgcn_rcpf(1.f + __expf(2.f * npre));
        const float hp = rcur ? 0.f : hprev[i][c];
        const float hnew = (1.f - z) * n + z * hp;
        hprev[i][c] = hnew;
        if (act) {
          ob0[(size_t)lt * 65536 + c * 128] = hnew;
          if (lt == wsteps - 1) h_carry[(size_t)b * 256 + c * 128 + wcb + n16] = hnew;
        }
        hbuf[wb][quad * 4 + i][c * 128 + wcb + n16] = nf ? (unsigned short)0 : f2bf(hnew);
      }
    }
    // LDS-only barrier: do NOT drain vmcnt (output stores + gi prefetch stay
    // in flight). hbuf exchange only needs lgkm ordering.
    __builtin_amdgcn_sched_barrier(0);
    asm volatile("s_waitcnt lgkmcnt(0)" ::: "memory");
    __builtin_amdgcn_s_barrier();
    __builtin_amdgcn_sched_barrier(0);
  };

  unsigned short A_[2][3][4], B_[2][3][4];
  prefetch(0, A_);
  for (int s = 0; s < smax; s += 2) {
    step(s, A_, B_);
    if (s + 1 < smax) step(s + 1, B_, A_);
  }
}

extern "C" void kernel_launch(void* const* d_in, const int* in_sizes, int n_in,
                              void* d_out, int out_size, void* d_ws, size_t ws_size,
                              hipStream_t stream) {
  const float* ins    = (const float*)d_in[0];
  const int* resets   = (const int*)d_in[1];
  const float* init_h = (const float*)d_in[2];
  const float* Wi     = (const float*)d_in[3];
  const float* Wh     = (const float*)d_in[4];
  const float* bias   = (const float*)d_in[5];
  float* out          = (float*)d_out;

  char* ws = (char*)d_ws;
  unsigned short* Wt  = (unsigned short*)ws;              // 393216 B
  unsigned short* Wht = (unsigned short*)(ws + 393216);   // 393216 B
  float* h_carry      = (float*)(ws + 786432);            // 262144 B
  unsigned short* gi  = (unsigned short*)(ws + 1048576);

  int wsteps = 1024;
  while (wsteps > 2 && (size_t)1048576 + (size_t)wsteps * 256 * 768 * 2 > ws_size) wsteps >>= 1;
  const int nwin = 1024 / wsteps;

  hipLaunchKernelGGL(transpose_w, dim3(384), dim3(256), 0, stream, Wi, Wh, Wt, Wht);
  for (int w = 0; w < nwin; ++w) {
    const int t0 = w * wsteps;
    hipLaunchKernelGGL(gi_gemm, dim3(wsteps * 2, 6), dim3(256), 0, stream, ins, Wt, gi, t0);
    hipLaunchKernelGGL(rec_kernel, dim3(256), dim3(512), 0, stream,
                       gi, resets, (w == 0 ? init_h : h_carry), h_carry, Wht, bias, out, t0, wsteps);
  }
}

// Round 3
// 931.680 us; speedup vs baseline: 4.7558x; 1.1399x over previous
//
#include <hip/hip_runtime.h>

// GRU scan T=1024,B=256,D=H=256 — 4-kernel design:
//  1) transpose_w: Wi,Wh (f32 [256][768]) -> Wt,Wht (bf16 [768][256], k-fast)
//  2) conv_bf16: ins f32 -> insb bf16 (one pass, memory-bound)
//  3) gi_gemm2: gi = insb @ Wt, m97-style: 128x128 tile, BK=32,
//     global_load_lds 16B staging (lane-linear, conflict-free), chunk-placed
//     LDS so frag reads hit bank slot row&7 (conflict-free), grid (6, M/128)
//     so the 6 N-tile sharers of each A-panel are dispatch-adjacent.
//  4) rec_kernel: chunk-parallel recurrence (resets cut the h-chain into 16
//     independent chunks per batch row). This round: pointer-increment gi
//     gather (no per-step mad64 addressing), carried reset flags, global
//     stores moved after the barrier.

typedef __attribute__((ext_vector_type(8))) short sv8;
typedef __attribute__((ext_vector_type(4))) short sv4;
typedef __attribute__((ext_vector_type(4))) float fv4;

#define HPAD 264

static __device__ __forceinline__ unsigned short f2bf(float f) {
  unsigned int u = __float_as_uint(f);
  u += 0x7fffu + ((u >> 16) & 1u);  // RNE
  return (unsigned short)(u >> 16);
}
static __device__ __forceinline__ float bf2f(unsigned short s) {
  return __uint_as_float(((unsigned int)s) << 16);
}

static __device__ __forceinline__ void gload16(const void* g, void* l) {
  __builtin_amdgcn_global_load_lds((__attribute__((address_space(1))) void*)g,
                                   (__attribute__((address_space(3))) void*)l,
                                   16, 0, 0);
}

// ---------------- kernel 1: weight transpose + bf16 cast ----------------
__global__ __launch_bounds__(256) void transpose_w(
    const float* __restrict__ Wi, const float* __restrict__ Wh,
    unsigned short* __restrict__ Wt, unsigned short* __restrict__ Wht) {
  __shared__ float tile[32][33];
  const int bid = blockIdx.x;                 // 0..383
  const float* src = (bid < 192) ? Wi : Wh;
  unsigned short* dst = (bid < 192) ? Wt : Wht;
  const int local = bid % 192;
  const int c0 = (local % 24) * 32;           // col in [0,768)
  const int k0 = (local / 24) * 32;           // k in [0,256)
  const int t = threadIdx.x, tr = t >> 5, tc = t & 31;
#pragma unroll
  for (int p = 0; p < 4; ++p) {
    int k = tr + p * 8;
    tile[k][tc] = src[(size_t)(k0 + k) * 768 + c0 + tc];
  }
  __syncthreads();
#pragma unroll
  for (int p = 0; p < 4; ++p) {
    int c = tr + p * 8;
    dst[(size_t)(c0 + c) * 256 + k0 + tc] = f2bf(tile[tc][c]);
  }
}

// ---------------- kernel 2: ins f32 -> bf16 ----------------
__global__ __launch_bounds__(256) void conv_bf16(
    const float* __restrict__ src, unsigned short* __restrict__ dst, int n8) {
  int i = blockIdx.x * 256 + threadIdx.x;
  const int stride = gridDim.x * 256;
  for (; i < n8; i += stride) {
    fv4 a = *(const fv4*)(src + (size_t)i * 8);
    fv4 b = *(const fv4*)(src + (size_t)i * 8 + 4);
    sv8 o = {(short)f2bf(a[0]), (short)f2bf(a[1]), (short)f2bf(a[2]), (short)f2bf(a[3]),
             (short)f2bf(b[0]), (short)f2bf(b[1]), (short)f2bf(b[2]), (short)f2bf(b[3])};
    *(sv8*)(dst + (size_t)i * 8) = o;
  }
}

// ---------------- kernel 3: gi = insb @ Wt (m97-style) ----------------
// grid (6, wsteps*2), 256 thr / 4 waves. BM=BN=128, BK=32.
// LDS chunk layout: chunk C (16B) at byte C*16 holds data for
//   row=(C>>5)*8+(C&7), kcol=((C>>3)&3)*8  -> frag read bank slot = row&7.
__global__ __launch_bounds__(256) void gi_gemm2(
    const unsigned short* __restrict__ insb,  // [T*B][256] bf16
    const unsigned short* __restrict__ Wt,    // [768][256] bf16
    unsigned short* __restrict__ gi, int w0) {
  __shared__ __align__(16) unsigned short As[4096];  // 128x32 chunk-placed
  __shared__ __align__(16) unsigned short Bs[4096];
  const int t = threadIdx.x;
  const int wave = t >> 6, lane = t & 63;
  const int n16 = lane & 15, quad = lane >> 4;
  const int n0 = blockIdx.x * 128;  // col tile (0..5)
  const int m0 = blockIdx.y * 128;  // row tile
  const int m0w = (wave & 1) * 64, n0w = (wave >> 1) * 64;

  // staging coords: wave issues instrs j=wave*2+{0,1}; chunk C=j*64+lane
  const int c0i = wave * 128 + lane;
  const int c1i = c0i + 64;
  const int r0 = ((c0i >> 5) << 3) | (c0i & 7), k0c = ((c0i >> 3) & 3) * 8;
  const int r1 = ((c1i >> 5) << 3) | (c1i & 7), k1c = ((c1i >> 3) & 3) * 8;
  unsigned short* ldA0 = As + (size_t)(wave * 2) * 512;
  unsigned short* ldA1 = As + (size_t)(wave * 2 + 1) * 512;
  unsigned short* ldB0 = Bs + (size_t)(wave * 2) * 512;
  unsigned short* ldB1 = Bs + (size_t)(wave * 2 + 1) * 512;
  const unsigned short* gA0 = insb + (size_t)(w0 * 256 + m0 + r0) * 256 + k0c;
  const unsigned short* gA1 = insb + (size_t)(w0 * 256 + m0 + r1) * 256 + k1c;
  const unsigned short* gB0 = Wt + (size_t)(n0 + r0) * 256 + k0c;
  const unsigned short* gB1 = Wt + (size_t)(n0 + r1) * 256 + k1c;

  // frag read bases (bytes): ((row>>3)<<9) | (quad<<7) | ((row&7)<<4)
  const int arow = m0w + n16, brow = n0w + n16;
  const char* apb = (const char*)As + ((arow >> 3) << 9) + (quad << 7) + ((arow & 7) << 4);
  const char* bpb = (const char*)Bs + ((brow >> 3) << 9) + (quad << 7) + ((brow & 7) << 4);

  fv4 acc[4][4] = {};
  for (int kb = 0; kb < 8; ++kb) {
    gload16(gA0 + kb * 32, ldA0);
    gload16(gA1 + kb * 32, ldA1);
    gload16(gB0 + kb * 32, ldB0);
    gload16(gB1 + kb * 32, ldB1);
    __syncthreads();
    sv8 af[4], bfr[4];
#pragma unroll
    for (int mt = 0; mt < 4; ++mt) af[mt] = *(const sv8*)(apb + mt * 1024);
#pragma unroll
    for (int nt = 0; nt < 4; ++nt) bfr[nt] = *(const sv8*)(bpb + nt * 1024);
#pragma unroll
    for (int mt = 0; mt < 4; ++mt)
#pragma unroll
      for (int nt = 0; nt < 4; ++nt)
        acc[mt][nt] = __builtin_amdgcn_mfma_f32_16x16x32_bf16(af[mt], bfr[nt], acc[mt][nt], 0, 0, 0);
    __syncthreads();
  }
#pragma unroll
  for (int mt = 0; mt < 4; ++mt)
#pragma unroll
    for (int i = 0; i < 4; ++i) {
      const int row = m0 + m0w + mt * 16 + quad * 4 + i;
      unsigned short* gp = gi + (size_t)row * 768 + n0 + n0w + n16;
#pragma unroll
      for (int nt = 0; nt < 4; ++nt) gp[nt * 16] = f2bf(acc[mt][nt][i]);
    }
}

// ---------------- kernel 4: chunk-parallel recurrent scan ----------------
// grid = 256 blocks (one per batch row), 512 thr (8 waves x 2 col-tiles).
__global__ __launch_bounds__(512, 2) void rec_kernel(
    const unsigned short* __restrict__ gi,   // [wsteps*256][768] bf16
    const int* __restrict__ resets,          // [T][B] int32
    const float* __restrict__ h_in,          // [B][H] f32
    float* __restrict__ h_carry,             // [B][H] f32
    const unsigned short* __restrict__ Wht,  // [768][256] bf16 transposed
    const float* __restrict__ bias,          // [768] f32
    float* __restrict__ out,                 // [T][B][H] f32
    int t0, int wsteps) {
  __shared__ __align__(16) unsigned short whn[256][HPAD];     // Wh_n, [col][k]
  __shared__ __align__(16) unsigned short hbuf[2][16][HPAD];  // h bf16 (16 chunks)
  __shared__ int rstl[1024];
  __shared__ int cand[16];
  __shared__ int cstart[17];
  __shared__ int s_smax;

  const int tid = threadIdx.x;
  const int wave = tid >> 6, lane = tid & 63;
  const int n16 = lane & 15, quad = lane >> 4;
  const int b = blockIdx.x;  // batch row owned by this block
  const int wcb = wave * 16;

  // stage Wh_n (cols 512..767 of Wht) into LDS
  for (int e = tid; e < 8192; e += 512) {
    const int col = e >> 5, kc = (e & 31) * 8;
    *(sv8*)&whn[col][kc] = *(const sv8*)(Wht + (size_t)(512 + col) * 256 + kc);
  }
  // stage this row's reset flags for the window
  for (int e = tid; e < wsteps; e += 512)
    rstl[e] = resets[(size_t)(t0 + e) * 256 + b];
  if (tid < 16) cand[tid] = wsteps;
  __syncthreads();

  // first reset per span
  {
    int span = wsteps >> 4;
    if (span < 1) span = 1;
    for (int e = tid; e < wsteps; e += 512)
      if (rstl[e]) {
        const int j = e / span;
        if (j < 16) atomicMin(&cand[j], e);
      }
  }
  // hbuf[0]: chunk 0 = bf16(h_in[b]) pre-masked by resets[t0]; rows 1..15 = 0
  {
    const int row = tid >> 5, c8 = (tid & 31) * 8;
    sv8 pk = {0, 0, 0, 0, 0, 0, 0, 0};
    if (row == 0 && !rstl[0]) {
      fv4 v0 = *(const fv4*)(h_in + (size_t)b * 256 + c8);
      fv4 v1 = *(const fv4*)(h_in + (size_t)b * 256 + c8 + 4);
#pragma unroll
      for (int j = 0; j < 4; ++j) pk[j] = (short)f2bf(v0[j]);
#pragma unroll
      for (int j = 0; j < 4; ++j) pk[4 + j] = (short)f2bf(v1[j]);
    }
    *(sv8*)&hbuf[0][row][c8] = pk;
  }
  __syncthreads();
  if (tid == 0) {
    // S[r] = first reset >= r*span (suffix-min over span candidates), dedup
    int S[17];
    S[16] = wsteps;
    for (int j = 15; j >= 0; --j) S[j] = (cand[j] < wsteps) ? cand[j] : S[j + 1];
    int cnt = 1;
    cstart[0] = 0;
    for (int r = 1; r < 16; ++r) {
      const int v = S[r];
      if (v < wsteps && v > cstart[cnt - 1]) cstart[cnt++] = v;
    }
    for (int r = cnt; r <= 16; ++r) cstart[r] = wsteps;
    int mx = 0;
    for (int r = 0; r < 16; ++r) {
      const int L = cstart[r + 1] - cstart[r];
      if (L > mx) mx = L;
    }
    s_smax = mx;
  }
  __syncthreads();

  int rs_[4], rl_[4];
#pragma unroll
  for (int i = 0; i < 4; ++i) {
    const int ri = quad * 4 + i;
    rs_[i] = cstart[ri];
    rl_[i] = cstart[ri + 1] - rs_[i];
  }
  float hprev[4][2];
#pragma unroll
  for (int i = 0; i < 4; ++i)
#pragma unroll
    for (int c = 0; c < 2; ++c)
      hprev[i][c] = (rs_[i] == 0) ? h_in[(size_t)b * 256 + c * 128 + wcb + n16] : 0.f;

  // Wh_r / Wh_z B-frags in VGPRs (256-reg budget at 8 waves)
  sv8 whf[2][2][8];
#pragma unroll
  for (int g = 0; g < 2; ++g)
#pragma unroll
    for (int c = 0; c < 2; ++c)
#pragma unroll
      for (int kt = 0; kt < 8; ++kt)
        whf[g][c][kt] = *(const sv8*)(Wht + (size_t)(g * 256 + c * 128 + wcb + n16) * 256 + kt * 32 + quad * 8);

  float b_r[2], b_z[2], b_n[2];
#pragma unroll
  for (int c = 0; c < 2; ++c) {
    const int col = c * 128 + wcb + n16;
    b_r[c] = bias[col];
    b_z[c] = bias[256 + col];
    b_n[c] = bias[512 + col];
  }

  // running per-chunk gather pointers (advance +196608 shorts per step)
  const size_t boff = (size_t)b * 768 + wcb + n16;
  const unsigned short* pmax = gi + (size_t)(wsteps - 1) * 196608 + boff;
  const unsigned short* gp[4];
#pragma unroll
  for (int i = 0; i < 4; ++i) {
    const int r0 = (rs_[i] < wsteps) ? rs_[i] : (wsteps - 1);
    gp[i] = gi + (size_t)r0 * 196608 + boff;
  }
  float* ob0 = out + (size_t)t0 * 65536 + (size_t)b * 256 + wcb + n16;
  const int smax = s_smax;

  // prefetch step 0
  unsigned short A_[2][3][4], B_[2][3][4];
#pragma unroll
  for (int i = 0; i < 4; ++i)
#pragma unroll
    for (int c = 0; c < 2; ++c) {
      A_[c][0][i] = gp[i][c * 128];
      A_[c][1][i] = gp[i][c * 128 + 256];
      A_[c][2][i] = gp[i][c * 128 + 512];
    }
  int rc[4];
#pragma unroll
  for (int i = 0; i < 4; ++i) rc[i] = (rl_[i] > 0) ? rstl[rs_[i]] : 1;

  auto step = [&](int s, unsigned short (&cur)[2][3][4], unsigned short (&nxt)[2][3][4]) {
    const int rb = s & 1, wb = rb ^ 1;
    fv4 acc[3][2] = {};
#pragma unroll
    for (int kt = 0; kt < 8; ++kt) {
      sv8 hf = *(const sv8*)&hbuf[rb][n16][kt * 32 + quad * 8];
#pragma unroll
      for (int c = 0; c < 2; ++c) {
        sv8 wnf = *(const sv8*)&whn[c * 128 + wcb + n16][kt * 32 + quad * 8];
        acc[0][c] = __builtin_amdgcn_mfma_f32_16x16x32_bf16(hf, whf[0][c][kt], acc[0][c], 0, 0, 0);
        acc[1][c] = __builtin_amdgcn_mfma_f32_16x16x32_bf16(hf, whf[1][c][kt], acc[1][c], 0, 0, 0);
        acc[2][c] = __builtin_amdgcn_mfma_f32_16x16x32_bf16(hf, wnf, acc[2][c], 0, 0, 0);
      }
    }
    // prefetch next step (pointer bump + imm-offset gathers; in flight across barrier)
#pragma unroll
    for (int i = 0; i < 4; ++i) {
      gp[i] += 196608;
      if (gp[i] > pmax) gp[i] = pmax;
#pragma unroll
      for (int c = 0; c < 2; ++c) {
        nxt[c][0][i] = gp[i][c * 128];
        nxt[c][1][i] = gp[i][c * 128 + 256];
        nxt[c][2][i] = gp[i][c * 128 + 512];
      }
    }
    int nf[4], lt[4];
    bool act[4];
    float hnew[4][2];
#pragma unroll
    for (int i = 0; i < 4; ++i) {
      lt[i] = rs_[i] + s;
      act[i] = (s < rl_[i]);
      nf[i] = (s + 1 < rl_[i]) ? rstl[lt[i] + 1] : 1;
#pragma unroll
      for (int c = 0; c < 2; ++c) {
        const float pre_r = bf2f(cur[c][0][i]) + acc[0][c][i] + b_r[c];
        const float pre_z = bf2f(cur[c][1][i]) + acc[1][c][i] + b_z[c];
        const float r = __builtin_amdgcn_rcpf(1.f + __expf(-pre_r));
        const float z = __builtin_amdgcn_rcpf(1.f + __expf(-pre_z));
        const float npre = bf2f(cur[c][2][i]) + r * (acc[2][c][i] + b_n[c]);
        const float n = 1.f - 2.f * __builtin_amdgcn_rcpf(1.f + __expf(2.f * npre));
        const float hp = rc[i] ? 0.f : hprev[i][c];
        const float h = (1.f - z) * n + z * hp;
        hnew[i][c] = h;
        hprev[i][c] = h;
        hbuf[wb][quad * 4 + i][c * 128 + wcb + n16] = nf[i] ? (unsigned short)0 : f2bf(h);
      }
    }
    // LDS-only barrier: hbuf exchange needs lgkm ordering only
    __builtin_amdgcn_sched_barrier(0);
    asm volatile("s_waitcnt lgkmcnt(0)" ::: "memory");
    __builtin_amdgcn_s_barrier();
    __builtin_amdgcn_sched_barrier(0);
    // post-barrier: fire-and-forget global stores (off the inter-barrier path)
#pragma unroll
    for (int i = 0; i < 4; ++i) {
      if (act[i]) {
#pragma unroll
        for (int c = 0; c < 2; ++c) {
          ob0[(size_t)lt[i] * 65536 + c * 128] = hnew[i][c];
          if (lt[i] == wsteps - 1)
            h_carry[(size_t)b * 256 + c * 128 + wcb + n16] = hnew[i][c];
        }
      }
      rc[i] = nf[i];
    }
  };

  for (int s = 0; s < smax; s += 2) {
    step(s, A_, B_);
    if (s + 1 < smax) step(s + 1, B_, A_);
  }
}

extern "C" void kernel_launch(void* const* d_in, const int* in_sizes, int n_in,
                              void* d_out, int out_size, void* d_ws, size_t ws_size,
                              hipStream_t stream) {
  const float* ins    = (const float*)d_in[0];
  const int* resets   = (const int*)d_in[1];
  const float* init_h = (const float*)d_in[2];
  const float* Wi     = (const float*)d_in[3];
  const float* Wh     = (const float*)d_in[4];
  const float* bias   = (const float*)d_in[5];
  float* out          = (float*)d_out;

  char* ws = (char*)d_ws;
  unsigned short* Wt   = (unsigned short*)ws;              // 393216 B
  unsigned short* Wht  = (unsigned short*)(ws + 393216);   // 393216 B
  float* h_carry       = (float*)(ws + 786432);            // 262144 B
  unsigned short* insb = (unsigned short*)(ws + 1048576);  // 134217728 B
  const size_t gi_off  = 1048576 + 134217728;
  unsigned short* gi   = (unsigned short*)(ws + gi_off);

  int wsteps = 1024;
  while (wsteps > 2 && gi_off + (size_t)wsteps * 256 * 768 * 2 > ws_size) wsteps >>= 1;
  const int nwin = 1024 / wsteps;

  hipLaunchKernelGGL(transpose_w, dim3(384), dim3(256), 0, stream, Wi, Wh, Wt, Wht);
  hipLaunchKernelGGL(conv_bf16, dim3(2048), dim3(256), 0, stream, ins, insb, 8388608);
  for (int w = 0; w < nwin; ++w) {
    const int t0 = w * wsteps;
    hipLaunchKernelGGL(gi_gemm2, dim3(6, wsteps * 2), dim3(256), 0, stream, insb, Wt, gi, t0);
    hipLaunchKernelGGL(rec_kernel, dim3(256), dim3(512), 0, stream,
                       gi, resets, (w == 0 ? init_h : h_carry), h_carry, Wht, bias, out, t0, wsteps);
  }
}

// Round 4
// 858.471 us; speedup vs baseline: 5.1614x; 1.0853x over previous
//
#include <hip/hip_runtime.h>

// GRU scan T=1024,B=256,D=H=256 — 4-kernel design:
//  1) transpose_w: Wi,Wh (f32 [256][768]) -> Wt,Wht (bf16 [768][256], k-fast)
//  2) conv_bf16: ins f32 -> insb bf16 (one pass, memory-bound)
//  3) gi_gemm3: gi = insb @ Wt. A-PANEL-REUSE: one block owns 128 rows x ALL
//     768 cols; full-K A panel staged once in LDS (64kB, chunk-placed,
//     global_load_lds 16B), B (L2-resident 393kB) streamed per (nt,kb).
//     A fetched exactly once from HBM (round-3 counter showed 3x re-fetch
//     from XCD-split L2s with the 6-way column grid).
//  4) rec_kernel: chunk-parallel recurrence (unchanged this round).

typedef __attribute__((ext_vector_type(8))) short sv8;
typedef __attribute__((ext_vector_type(4))) short sv4;
typedef __attribute__((ext_vector_type(4))) float fv4;

#define HPAD 264

static __device__ __forceinline__ unsigned short f2bf(float f) {
  unsigned int u = __float_as_uint(f);
  u += 0x7fffu + ((u >> 16) & 1u);  // RNE
  return (unsigned short)(u >> 16);
}
static __device__ __forceinline__ float bf2f(unsigned short s) {
  return __uint_as_float(((unsigned int)s) << 16);
}

static __device__ __forceinline__ void gload16(const void* g, void* l) {
  __builtin_amdgcn_global_load_lds((__attribute__((address_space(1))) void*)g,
                                   (__attribute__((address_space(3))) void*)l,
                                   16, 0, 0);
}

// ---------------- kernel 1: weight transpose + bf16 cast ----------------
__global__ __launch_bounds__(256) void transpose_w(
    const float* __restrict__ Wi, const float* __restrict__ Wh,
    unsigned short* __restrict__ Wt, unsigned short* __restrict__ Wht) {
  __shared__ float tile[32][33];
  const int bid = blockIdx.x;                 // 0..383
  const float* src = (bid < 192) ? Wi : Wh;
  unsigned short* dst = (bid < 192) ? Wt : Wht;
  const int local = bid % 192;
  const int c0 = (local % 24) * 32;           // col in [0,768)
  const int k0 = (local / 24) * 32;           // k in [0,256)
  const int t = threadIdx.x, tr = t >> 5, tc = t & 31;
#pragma unroll
  for (int p = 0; p < 4; ++p) {
    int k = tr + p * 8;
    tile[k][tc] = src[(size_t)(k0 + k) * 768 + c0 + tc];
  }
  __syncthreads();
#pragma unroll
  for (int p = 0; p < 4; ++p) {
    int c = tr + p * 8;
    dst[(size_t)(c0 + c) * 256 + k0 + tc] = f2bf(tile[tc][c]);
  }
}

// ---------------- kernel 2: ins f32 -> bf16 ----------------
__global__ __launch_bounds__(256) void conv_bf16(
    const float* __restrict__ src, unsigned short* __restrict__ dst, int n8) {
  int i = blockIdx.x * 256 + threadIdx.x;
  const int stride = gridDim.x * 256;
  for (; i < n8; i += stride) {
    fv4 a = *(const fv4*)(src + (size_t)i * 8);
    fv4 b = *(const fv4*)(src + (size_t)i * 8 + 4);
    sv8 o = {(short)f2bf(a[0]), (short)f2bf(a[1]), (short)f2bf(a[2]), (short)f2bf(a[3]),
             (short)f2bf(b[0]), (short)f2bf(b[1]), (short)f2bf(b[2]), (short)f2bf(b[3])};
    *(sv8*)(dst + (size_t)i * 8) = o;
  }
}

// ---------------- kernel 3: gi = insb @ Wt (A-panel reuse) ----------------
// grid (M/128), 256 thr / 4 waves. Block: rows [m0,m0+128) x cols [0,768).
// LDS chunk layout per 128x32 subtile: chunk C (16B) at byte C*16 holds
//   row=(C>>5)*8+(C&7), kcol=((C>>3)&3)*8  -> frag reads land on bank slot
//   row&7 (measured conflict-free in round 3).
__global__ __launch_bounds__(256, 2) void gi_gemm3(
    const unsigned short* __restrict__ insb,  // [T*B][256] bf16
    const unsigned short* __restrict__ Wt,    // [768][256] bf16
    unsigned short* __restrict__ gi, int w0) {
  __shared__ __align__(16) unsigned short As[32768];  // 8 subtiles x 8192B
  __shared__ __align__(16) unsigned short Bs[4096];   // one 128x32 subtile
  const int t = threadIdx.x;
  const int wave = t >> 6, lane = t & 63;
  const int n16 = lane & 15, quad = lane >> 4;
  const int m0 = blockIdx.x * 128;
  const int m0w = (wave & 1) * 64, n0w = (wave >> 1) * 64;

  // staging coords: wave issues chunks C=wave*128+lane and +64
  const int c0i = wave * 128 + lane;
  const int c1i = c0i + 64;
  const int r0 = ((c0i >> 5) << 3) | (c0i & 7), k0c = ((c0i >> 3) & 3) * 8;
  const int r1 = ((c1i >> 5) << 3) | (c1i & 7), k1c = ((c1i >> 3) & 3) * 8;

  // ---- A prologue: full-K panel, 16x gload16, staged once ----
  {
    const unsigned short* gA0 = insb + (size_t)(w0 * 256 + m0 + r0) * 256 + k0c;
    const unsigned short* gA1 = insb + (size_t)(w0 * 256 + m0 + r1) * 256 + k1c;
    unsigned short* dA0 = As + wave * 1024;
    unsigned short* dA1 = dA0 + 512;
#pragma unroll
    for (int kb = 0; kb < 8; ++kb) {
      gload16(gA0 + kb * 32, dA0 + kb * 4096);
      gload16(gA1 + kb * 32, dA1 + kb * 4096);
    }
  }
  // ---- first B subtile (nt=0, kb=0) ----
  const unsigned short* gB0 = Wt + (size_t)r0 * 256 + k0c;
  const unsigned short* gB1 = Wt + (size_t)r1 * 256 + k1c;
  unsigned short* dB0 = Bs + wave * 1024;
  unsigned short* dB1 = dB0 + 512;
  gload16(gB0, dB0);
  gload16(gB1, dB1);
  __syncthreads();  // drains vmcnt: A panel + B(0,0) resident

  // frag read bases (bytes): ((row>>3)<<9) | (quad<<7) | ((row&7)<<4)
  const int arow = m0w + n16, brow = n0w + n16;
  const char* apb = (const char*)As + ((arow >> 3) << 9) + (quad << 7) + ((arow & 7) << 4);
  const char* bpb = (const char*)Bs + ((brow >> 3) << 9) + (quad << 7) + ((brow & 7) << 4);

  for (int nt = 0; nt < 6; ++nt) {
    fv4 acc[4][4] = {};
#pragma unroll
    for (int kb = 0; kb < 8; ++kb) {
      sv8 af[4], bfr[4];
#pragma unroll
      for (int mt = 0; mt < 4; ++mt) af[mt] = *(const sv8*)(apb + kb * 8192 + mt * 1024);
#pragma unroll
      for (int j = 0; j < 4; ++j) bfr[j] = *(const sv8*)(bpb + j * 1024);
#pragma unroll
      for (int mt = 0; mt < 4; ++mt)
#pragma unroll
        for (int j = 0; j < 4; ++j)
          acc[mt][j] = __builtin_amdgcn_mfma_f32_16x16x32_bf16(af[mt], bfr[j], acc[mt][j], 0, 0, 0);
      __syncthreads();  // all waves done reading Bs
      const int step = nt * 8 + kb + 1;
      if (step < 48) {
        const int nn = step >> 3, nk = step & 7;
        gload16(gB0 + (size_t)nn * 32768 + nk * 32, dB0);
        gload16(gB1 + (size_t)nn * 32768 + nk * 32, dB1);
      }
      __syncthreads();  // staging complete (vmcnt drained before barrier)
    }
    // epilogue for this 128x128 column tile
#pragma unroll
    for (int mt = 0; mt < 4; ++mt)
#pragma unroll
      for (int i = 0; i < 4; ++i) {
        const int row = m0 + m0w + mt * 16 + quad * 4 + i;
        unsigned short* gp = gi + (size_t)row * 768 + nt * 128 + n0w + n16;
#pragma unroll
        for (int j = 0; j < 4; ++j) gp[j * 16] = f2bf(acc[mt][j][i]);
      }
  }
}

// ---------------- kernel 4: chunk-parallel recurrent scan ----------------
// grid = 256 blocks (one per batch row), 512 thr (8 waves x 2 col-tiles).
__global__ __launch_bounds__(512, 2) void rec_kernel(
    const unsigned short* __restrict__ gi,   // [wsteps*256][768] bf16
    const int* __restrict__ resets,          // [T][B] int32
    const float* __restrict__ h_in,          // [B][H] f32
    float* __restrict__ h_carry,             // [B][H] f32
    const unsigned short* __restrict__ Wht,  // [768][256] bf16 transposed
    const float* __restrict__ bias,          // [768] f32
    float* __restrict__ out,                 // [T][B][H] f32
    int t0, int wsteps) {
  __shared__ __align__(16) unsigned short whn[256][HPAD];     // Wh_n, [col][k]
  __shared__ __align__(16) unsigned short hbuf[2][16][HPAD];  // h bf16 (16 chunks)
  __shared__ int rstl[1024];
  __shared__ int cand[16];
  __shared__ int cstart[17];
  __shared__ int s_smax;

  const int tid = threadIdx.x;
  const int wave = tid >> 6, lane = tid & 63;
  const int n16 = lane & 15, quad = lane >> 4;
  const int b = blockIdx.x;  // batch row owned by this block
  const int wcb = wave * 16;

  // stage Wh_n (cols 512..767 of Wht) into LDS
  for (int e = tid; e < 8192; e += 512) {
    const int col = e >> 5, kc = (e & 31) * 8;
    *(sv8*)&whn[col][kc] = *(const sv8*)(Wht + (size_t)(512 + col) * 256 + kc);
  }
  // stage this row's reset flags for the window
  for (int e = tid; e < wsteps; e += 512)
    rstl[e] = resets[(size_t)(t0 + e) * 256 + b];
  if (tid < 16) cand[tid] = wsteps;
  __syncthreads();

  // first reset per span
  {
    int span = wsteps >> 4;
    if (span < 1) span = 1;
    for (int e = tid; e < wsteps; e += 512)
      if (rstl[e]) {
        const int j = e / span;
        if (j < 16) atomicMin(&cand[j], e);
      }
  }
  // hbuf[0]: chunk 0 = bf16(h_in[b]) pre-masked by resets[t0]; rows 1..15 = 0
  {
    const int row = tid >> 5, c8 = (tid & 31) * 8;
    sv8 pk = {0, 0, 0, 0, 0, 0, 0, 0};
    if (row == 0 && !rstl[0]) {
      fv4 v0 = *(const fv4*)(h_in + (size_t)b * 256 + c8);
      fv4 v1 = *(const fv4*)(h_in + (size_t)b * 256 + c8 + 4);
#pragma unroll
      for (int j = 0; j < 4; ++j) pk[j] = (short)f2bf(v0[j]);
#pragma unroll
      for (int j = 0; j < 4; ++j) pk[4 + j] = (short)f2bf(v1[j]);
    }
    *(sv8*)&hbuf[0][row][c8] = pk;
  }
  __syncthreads();
  if (tid == 0) {
    // S[r] = first reset >= r*span (suffix-min over span candidates), dedup
    int S[17];
    S[16] = wsteps;
    for (int j = 15; j >= 0; --j) S[j] = (cand[j] < wsteps) ? cand[j] : S[j + 1];
    int cnt = 1;
    cstart[0] = 0;
    for (int r = 1; r < 16; ++r) {
      const int v = S[r];
      if (v < wsteps && v > cstart[cnt - 1]) cstart[cnt++] = v;
    }
    for (int r = cnt; r <= 16; ++r) cstart[r] = wsteps;
    int mx = 0;
    for (int r = 0; r < 16; ++r) {
      const int L = cstart[r + 1] - cstart[r];
      if (L > mx) mx = L;
    }
    s_smax = mx;
  }
  __syncthreads();

  int rs_[4], rl_[4];
#pragma unroll
  for (int i = 0; i < 4; ++i) {
    const int ri = quad * 4 + i;
    rs_[i] = cstart[ri];
    rl_[i] = cstart[ri + 1] - rs_[i];
  }
  float hprev[4][2];
#pragma unroll
  for (int i = 0; i < 4; ++i)
#pragma unroll
    for (int c = 0; c < 2; ++c)
      hprev[i][c] = (rs_[i] == 0) ? h_in[(size_t)b * 256 + c * 128 + wcb + n16] : 0.f;

  // Wh_r / Wh_z B-frags in VGPRs (256-reg budget at 8 waves)
  sv8 whf[2][2][8];
#pragma unroll
  for (int g = 0; g < 2; ++g)
#pragma unroll
    for (int c = 0; c < 2; ++c)
#pragma unroll
      for (int kt = 0; kt < 8; ++kt)
        whf[g][c][kt] = *(const sv8*)(Wht + (size_t)(g * 256 + c * 128 + wcb + n16) * 256 + kt * 32 + quad * 8);

  float b_r[2], b_z[2], b_n[2];
#pragma unroll
  for (int c = 0; c < 2; ++c) {
    const int col = c * 128 + wcb + n16;
    b_r[c] = bias[col];
    b_z[c] = bias[256 + col];
    b_n[c] = bias[512 + col];
  }

  // running per-chunk gather pointers (advance +196608 shorts per step)
  const size_t boff = (size_t)b * 768 + wcb + n16;
  const unsigned short* pmax = gi + (size_t)(wsteps - 1) * 196608 + boff;
  const unsigned short* gp[4];
#pragma unroll
  for (int i = 0; i < 4; ++i) {
    const int r0 = (rs_[i] < wsteps) ? rs_[i] : (wsteps - 1);
    gp[i] = gi + (size_t)r0 * 196608 + boff;
  }
  float* ob0 = out + (size_t)t0 * 65536 + (size_t)b * 256 + wcb + n16;
  const int smax = s_smax;

  // prefetch step 0
  unsigned short A_[2][3][4], B_[2][3][4];
#pragma unroll
  for (int i = 0; i < 4; ++i)
#pragma unroll
    for (int c = 0; c < 2; ++c) {
      A_[c][0][i] = gp[i][c * 128];
      A_[c][1][i] = gp[i][c * 128 + 256];
      A_[c][2][i] = gp[i][c * 128 + 512];
    }
  int rc[4];
#pragma unroll
  for (int i = 0; i < 4; ++i) rc[i] = (rl_[i] > 0) ? rstl[rs_[i]] : 1;

  auto step = [&](int s, unsigned short (&cur)[2][3][4], unsigned short (&nxt)[2][3][4]) {
    const int rb = s & 1, wb = rb ^ 1;
    fv4 acc[3][2] = {};
#pragma unroll
    for (int kt = 0; kt < 8; ++kt) {
      sv8 hf = *(const sv8*)&hbuf[rb][n16][kt * 32 + quad * 8];
#pragma unroll
      for (int c = 0; c < 2; ++c) {
        sv8 wnf = *(const sv8*)&whn[c * 128 + wcb + n16][kt * 32 + quad * 8];
        acc[0][c] = __builtin_amdgcn_mfma_f32_16x16x32_bf16(hf, whf[0][c][kt], acc[0][c], 0, 0, 0);
        acc[1][c] = __builtin_amdgcn_mfma_f32_16x16x32_bf16(hf, whf[1][c][kt], acc[1][c], 0, 0, 0);
        acc[2][c] = __builtin_amdgcn_mfma_f32_16x16x32_bf16(hf, wnf, acc[2][c], 0, 0, 0);
      }
    }
    // prefetch next step (pointer bump + imm-offset gathers; in flight across barrier)
#pragma unroll
    for (int i = 0; i < 4; ++i) {
      gp[i] += 196608;
      if (gp[i] > pmax) gp[i] = pmax;
#pragma unroll
      for (int c = 0; c < 2; ++c) {
        nxt[c][0][i] = gp[i][c * 128];
        nxt[c][1][i] = gp[i][c * 128 + 256];
        nxt[c][2][i] = gp[i][c * 128 + 512];
      }
    }
    int nf[4], lt[4];
    bool act[4];
    float hnew[4][2];
#pragma unroll
    for (int i = 0; i < 4; ++i) {
      lt[i] = rs_[i] + s;
      act[i] = (s < rl_[i]);
      nf[i] = (s + 1 < rl_[i]) ? rstl[lt[i] + 1] : 1;
#pragma unroll
      for (int c = 0; c < 2; ++c) {
        const float pre_r = bf2f(cur[c][0][i]) + acc[0][c][i] + b_r[c];
        const float pre_z = bf2f(cur[c][1][i]) + acc[1][c][i] + b_z[c];
        const float r = __builtin_amdgcn_rcpf(1.f + __expf(-pre_r));
        const float z = __builtin_amdgcn_rcpf(1.f + __expf(-pre_z));
        const float npre = bf2f(cur[c][2][i]) + r * (acc[2][c][i] + b_n[c]);
        const float n = 1.f - 2.f * __builtin_amdgcn_rcpf(1.f + __expf(2.f * npre));
        const float hp = rc[i] ? 0.f : hprev[i][c];
        const float h = (1.f - z) * n + z * hp;
        hnew[i][c] = h;
        hprev[i][c] = h;
        hbuf[wb][quad * 4 + i][c * 128 + wcb + n16] = nf[i] ? (unsigned short)0 : f2bf(h);
      }
    }
    // LDS-only barrier: hbuf exchange needs lgkm ordering only
    __builtin_amdgcn_sched_barrier(0);
    asm volatile("s_waitcnt lgkmcnt(0)" ::: "memory");
    __builtin_amdgcn_s_barrier();
    __builtin_amdgcn_sched_barrier(0);
    // post-barrier: fire-and-forget global stores (off the inter-barrier path)
#pragma unroll
    for (int i = 0; i < 4; ++i) {
      if (act[i]) {
#pragma unroll
        for (int c = 0; c < 2; ++c) {
          ob0[(size_t)lt[i] * 65536 + c * 128] = hnew[i][c];
          if (lt[i] == wsteps - 1)
            h_carry[(size_t)b * 256 + c * 128 + wcb + n16] = hnew[i][c];
        }
      }
      rc[i] = nf[i];
    }
  };

  for (int s = 0; s < smax; s += 2) {
    step(s, A_, B_);
    if (s + 1 < smax) step(s + 1, B_, A_);
  }
}

extern "C" void kernel_launch(void* const* d_in, const int* in_sizes, int n_in,
                              void* d_out, int out_size, void* d_ws, size_t ws_size,
                              hipStream_t stream) {
  const float* ins    = (const float*)d_in[0];
  const int* resets   = (const int*)d_in[1];
  const float* init_h = (const float*)d_in[2];
  const float* Wi     = (const float*)d_in[3];
  const float* Wh     = (const float*)d_in[4];
  const float* bias   = (const float*)d_in[5];
  float* out          = (float*)d_out;

  char* ws = (char*)d_ws;
  unsigned short* Wt   = (unsigned short*)ws;              // 393216 B
  unsigned short* Wht  = (unsigned short*)(ws + 393216);   // 393216 B
  float* h_carry       = (float*)(ws + 786432);            // 262144 B
  unsigned short* insb = (unsigned short*)(ws + 1048576);  // 134217728 B
  const size_t gi_off  = 1048576 + 134217728;
  unsigned short* gi   = (unsigned short*)(ws + gi_off);

  int wsteps = 1024;
  while (wsteps > 2 && gi_off + (size_t)wsteps * 256 * 768 * 2 > ws_size) wsteps >>= 1;
  const int nwin = 1024 / wsteps;

  hipLaunchKernelGGL(transpose_w, dim3(384), dim3(256), 0, stream, Wi, Wh, Wt, Wht);
  hipLaunchKernelGGL(conv_bf16, dim3(2048), dim3(256), 0, stream, ins, insb, 8388608);
  for (int w = 0; w < nwin; ++w) {
    const int t0 = w * wsteps;
    hipLaunchKernelGGL(gi_gemm3, dim3(wsteps * 2), dim3(256), 0, stream, insb, Wt, gi, t0);
    hipLaunchKernelGGL(rec_kernel, dim3(256), dim3(512), 0, stream,
                       gi, resets, (w == 0 ? init_h : h_carry), h_carry, Wht, bias, out, t0, wsteps);
  }
}